// Round 1
// baseline (6195.988 us; speedup 1.0000x reference)
//
#include <hip/hip_runtime.h>

#define T_STEPS 63
#define NWG 256
#define WG_SIZE 256

typedef float floatx4 __attribute__((ext_vector_type(4)));
typedef __bf16 bf16x8 __attribute__((ext_vector_type(8)));

__device__ __forceinline__ unsigned short f2bf(float x) {
  unsigned int u = __builtin_bit_cast(unsigned int, x);
  u += 0x7fffu + ((u >> 16) & 1u);
  return (unsigned short)(u >> 16);
}
__device__ __forceinline__ float bf2f(unsigned short h) {
  unsigned int u = ((unsigned int)h) << 16;
  return __builtin_bit_cast(float, u);
}
__device__ __forceinline__ float sigmoidf(float x) {
  return 1.0f / (1.0f + __expf(-x));
}
__device__ __forceinline__ floatx4 mfma_bf16(bf16x8 a, bf16x8 b, floatx4 c) {
  return __builtin_amdgcn_mfma_f32_16x16x32_bf16(a, b, c, 0, 0, 0);
}

// ---- lightweight grid barrier (cooperative launch guarantees co-residency) ----
__device__ __forceinline__ void gbar(int* bars, int id, int n) {
  __syncthreads();
  if (threadIdx.x == 0) {
    __builtin_amdgcn_fence(__ATOMIC_RELEASE, "agent");
    __hip_atomic_fetch_add(bars + id, 1, __ATOMIC_RELAXED, __HIP_MEMORY_SCOPE_AGENT);
    while (__hip_atomic_load(bars + id, __ATOMIC_RELAXED, __HIP_MEMORY_SCOPE_AGENT) < n)
      __builtin_amdgcn_s_sleep(1);
    __builtin_amdgcn_fence(__ATOMIC_ACQUIRE, "agent");
  }
  __syncthreads();
}

// ---- prologue: tiled transpose fp32 -> bf16.  out[c*ostride + ooff + r] = bf16(in[r*C+c])
__global__ void k_transpose(const float* __restrict__ in, unsigned short* __restrict__ out,
                            int R, int C, int ostride, int ooff) {
  __shared__ unsigned short tile[64][65];
  const int r0 = blockIdx.x << 6, c0 = blockIdx.y << 6;
  const int t = threadIdx.x;
  const int tr4 = t >> 6, tc = t & 63;
#pragma unroll
  for (int p = 0; p < 16; ++p) {
    int i = (p << 2) + tr4;
    int r = r0 + i;
    unsigned short v = 0;
    if (r < R) v = f2bf(in[(size_t)r * C + (c0 + tc)]);
    tile[i][tc] = v;
  }
  __syncthreads();
#pragma unroll
  for (int p = 0; p < 16; ++p) {
    int j = (p << 2) + tr4;
    int r = r0 + tc;
    if (r < R) out[(size_t)(c0 + j) * ostride + ooff + r] = tile[tc][j];
  }
}

// ---- prologue: init xh (emb0 = E[0], content, style) and out[:,0,:] = E[0]
__global__ void k_init(const float* __restrict__ content, const float* __restrict__ style,
                       const float* __restrict__ E, unsigned short* xh, float* out) {
  const int stride = gridDim.x * blockDim.x;
  const int idx = blockIdx.x * blockDim.x + threadIdx.x;
  for (int i = idx; i < 32 * 656; i += stride) {
    int b = i / 656, k = i - b * 656;
    float v;
    if (k < 512)      v = E[k];
    else if (k < 640) v = content[b * 128 + (k - 512)];
    else              v = style[b * 16 + (k - 640)];
    xh[b * 1184 + k] = f2bf(v);
  }
  for (int i = idx; i < 32 * 512; i += stride) {
    int b = i >> 9, d = i & 511;
    out[(size_t)b * (64 * 512) + d] = E[d];
  }
}

// ---- main persistent cooperative kernel ----
__global__ void __launch_bounds__(WG_SIZE, 1) k_main(
    const float* __restrict__ bvec,   // [2048]
    const float* __restrict__ bs,     // [32000]
    const unsigned short* __restrict__ WsT,   // [32000][512] bf16 (Ws^T)
    const unsigned short* __restrict__ EbT,   // [512][32000]  bf16 (E^T)
    const unsigned short* __restrict__ WkrT,  // [2048][1184]  bf16 ([Wk;Wr]^T, k-padded)
    unsigned short* xh,      // [32][1184] bf16: emb | content | style | h | pad
    unsigned short* h_buf,   // [32][512] bf16
    float* c_state,          // [32][512] fp32
    unsigned short* u_part,  // [250][32][512] bf16
    float* Z_part,           // [250][32] fp32
    int* bars, float* out)
{
  const int wg = blockIdx.x;
  const int t  = threadIdx.x;
  const int wv = t >> 6;
  const int lane = t & 63;
  const int q = lane >> 4;
  const int m16 = lane & 15;

  __shared__ __align__(16) char smem[9216];
  unsigned short (*e_lds)[136] = (unsigned short (*)[136])smem;  // 8704 B
  float (*zbuf)[16][17] = (float (*)[16][17])smem;               // 4352 B
  float (*red)[4] = (float (*)[4])smem;                          // 1024 B
  float* zred = (float*)(smem + 1024);                           // 1024 B

  int bar_id = 0;
  for (int s = 0; s < T_STEPS; ++s) {
    // ---------------- phase A: z = xh @ Wkr + b ; LSTM pointwise -> h_buf, c_state
    if (wg < 64) {
      const int dt = wg >> 1, mt = wg & 1;
      const int n = wv * 512 + dt * 16 + m16;   // wave = gate
      floatx4 acc = {0.f, 0.f, 0.f, 0.f};
      const unsigned short* arow = xh + (mt * 16 + m16) * 1184 + q * 8;
      const unsigned short* brow = WkrT + (size_t)n * 1184 + q * 8;
#pragma unroll 4
      for (int ks = 0; ks < 37; ++ks) {
        bf16x8 a  = *(const bf16x8*)(arow + ks * 32);
        bf16x8 bb = *(const bf16x8*)(brow + ks * 32);
        acc = mfma_bf16(a, bb, acc);
      }
      const float bias = bvec[n];
#pragma unroll
      for (int r = 0; r < 4; ++r) zbuf[wv][q * 4 + r][m16] = acc[r] + bias;
      __syncthreads();
      {
        const int r = t >> 4, cc = t & 15;
        const int br = mt * 16 + r, d = dt * 16 + cc;
        const float iv = sigmoidf(zbuf[0][r][cc]);
        const float fv = sigmoidf(zbuf[1][r][cc]);
        const float gv = tanhf(zbuf[2][r][cc]);
        const float ov = sigmoidf(zbuf[3][r][cc]);
        const int ix = br * 512 + d;
        const float c = fv * c_state[ix] + iv * gv;
        c_state[ix] = c;
        h_buf[ix] = f2bf(ov * tanhf(c));
      }
    }
    gbar(bars, bar_id++, NWG);

    // ---------------- phase B: per-WG 128-word vocab slice
    if (wg < 250) {
      const int jbase = wg * 128;
      floatx4 acc1[2][2] = {};
      const unsigned short* a0p = h_buf + m16 * 512 + q * 8;
      const unsigned short* a1p = h_buf + (16 + m16) * 512 + q * 8;
      const unsigned short* b0p = WsT + (size_t)(jbase + (wv * 2) * 16 + m16) * 512 + q * 8;
      const unsigned short* b1p = WsT + (size_t)(jbase + (wv * 2 + 1) * 16 + m16) * 512 + q * 8;
#pragma unroll 4
      for (int ks = 0; ks < 16; ++ks) {
        bf16x8 a0 = *(const bf16x8*)(a0p + ks * 32);
        bf16x8 a1 = *(const bf16x8*)(a1p + ks * 32);
        bf16x8 w0 = *(const bf16x8*)(b0p + ks * 32);
        bf16x8 w1 = *(const bf16x8*)(b1p + ks * 32);
        acc1[0][0] = mfma_bf16(a0, w0, acc1[0][0]);
        acc1[1][0] = mfma_bf16(a1, w0, acc1[1][0]);
        acc1[0][1] = mfma_bf16(a0, w1, acc1[0][1]);
        acc1[1][1] = mfma_bf16(a1, w1, acc1[1][1]);
      }
      // exp(logits + bs) -> e_lds (bf16), C/D layout -> row-major
#pragma unroll
      for (int ni = 0; ni < 2; ++ni) {
        const int ntl = (wv * 2 + ni) * 16 + m16;   // local col 0..127
        const float bsv = bs[jbase + ntl];
#pragma unroll
        for (int mt2 = 0; mt2 < 2; ++mt2)
#pragma unroll
          for (int r = 0; r < 4; ++r)
            e_lds[mt2 * 16 + q * 4 + r][ntl] = f2bf(__expf(acc1[mt2][ni][r] + bsv));
      }
      __syncthreads();
      if (t < 32) {  // Z partial per batch row
        float zsum = 0.f;
        for (int j = 0; j < 128; ++j) zsum += bf2f(e_lds[t][j]);
        Z_part[wg * 32 + t] = zsum;
      }
      // u_partial = e @ E_tile  (A from LDS, B from E^T rows)
      floatx4 acc2[2][8] = {};
#pragma unroll 2
      for (int ks = 0; ks < 4; ++ks) {
        bf16x8 a0 = *(const bf16x8*)(&e_lds[m16][ks * 32 + q * 8]);
        bf16x8 a1 = *(const bf16x8*)(&e_lds[16 + m16][ks * 32 + q * 8]);
#pragma unroll
        for (int ni = 0; ni < 8; ++ni) {
          const int d = (wv * 8 + ni) * 16 + m16;
          bf16x8 eb = *(const bf16x8*)(EbT + (size_t)d * 32000 + jbase + ks * 32 + q * 8);
          acc2[0][ni] = mfma_bf16(a0, eb, acc2[0][ni]);
          acc2[1][ni] = mfma_bf16(a1, eb, acc2[1][ni]);
        }
      }
#pragma unroll
      for (int mt2 = 0; mt2 < 2; ++mt2)
#pragma unroll
        for (int ni = 0; ni < 8; ++ni)
#pragma unroll
          for (int r = 0; r < 4; ++r) {
            const int b = mt2 * 16 + q * 4 + r;
            const int d = (wv * 8 + ni) * 16 + m16;
            u_part[((size_t)wg * 32 + b) * 512 + d] = f2bf(acc2[mt2][ni][r]);
          }
    }
    gbar(bars, bar_id++, NWG);

    // ---------------- phase C: reduce partials -> emb ; stage next xh
    {
      const int tl = t & 63;
      const int o = wg * 64 + tl;          // flat output index, all same b per WG
      const int b = o >> 9, d = o & 511;
      zred[t] = (t < 250) ? Z_part[t * 32 + b] : 0.f;
      __syncthreads();
      for (int st = 128; st > 0; st >>= 1) {
        if (t < st) zred[t] += zred[t + st];
        __syncthreads();
      }
      const float invZ = 1.0f / zred[0];
      float ssum = 0.f;
      const int p0 = wv * 63;
      const int p1 = (wv == 3) ? 250 : (p0 + 63);
      for (int p = p0; p < p1; ++p)
        ssum += bf2f(u_part[((size_t)p * 32 + b) * 512 + d]);
      red[tl][wv] = ssum;
      __syncthreads();
      if (t < 64) {
        const float emb = (red[t][0] + red[t][1] + red[t][2] + red[t][3]) * invZ;
        out[(size_t)b * (64 * 512) + (size_t)(s + 1) * 512 + d] = emb;
        xh[b * 1184 + d] = f2bf(emb);
        xh[b * 1184 + 656 + d] = h_buf[b * 512 + d];
      }
    }
    if (s < T_STEPS - 1) gbar(bars, bar_id++, NWG);
  }
}

// ---------------- host ----------------
extern "C" void kernel_launch(void* const* d_in, const int* in_sizes, int n_in,
                              void* d_out, int out_size, void* d_ws, size_t ws_size,
                              hipStream_t stream) {
  const float* content = (const float*)d_in[0];
  const float* style   = (const float*)d_in[1];
  const float* E       = (const float*)d_in[2];
  const float* Wk      = (const float*)d_in[3];
  const float* Wr      = (const float*)d_in[4];
  const float* bvec    = (const float*)d_in[5];
  const float* Ws      = (const float*)d_in[6];
  const float* bs      = (const float*)d_in[7];
  float* out = (float*)d_out;
  char* ws = (char*)d_ws;

  constexpr size_t SZ_WST  = 32000ull * 512 * 2;       // 32,768,000
  constexpr size_t SZ_EBT  = 512ull * 32000 * 2;       // 32,768,000
  constexpr size_t SZ_WKRT = 2048ull * 1184 * 2;       //  4,849,664
  constexpr size_t SZ_XH   = 32ull * 1184 * 2;         //     75,776
  constexpr size_t SZ_HBUF = 32ull * 512 * 2;          //     32,768
  constexpr size_t SZ_CST  = 32ull * 512 * 4;          //     65,536
  constexpr size_t SZ_UP   = 250ull * 32 * 512 * 2;    //  8,192,000
  constexpr size_t SZ_ZP   = 250ull * 32 * 4;          //     32,000
  constexpr size_t OFF_WST  = 0;
  constexpr size_t OFF_EBT  = OFF_WST + SZ_WST;
  constexpr size_t OFF_WKRT = OFF_EBT + SZ_EBT;
  constexpr size_t OFF_XH   = OFF_WKRT + SZ_WKRT;
  constexpr size_t OFF_HBUF = OFF_XH + SZ_XH;
  constexpr size_t OFF_CST  = OFF_HBUF + SZ_HBUF;
  constexpr size_t OFF_UP   = OFF_CST + SZ_CST;
  constexpr size_t OFF_ZP   = OFF_UP + SZ_UP;
  constexpr size_t OFF_BARS = OFF_ZP + SZ_ZP + 256;    // keep 256-B alignment slack

  unsigned short* WsT   = (unsigned short*)(ws + OFF_WST);
  unsigned short* EbT   = (unsigned short*)(ws + OFF_EBT);
  unsigned short* WkrT  = (unsigned short*)(ws + OFF_WKRT);
  unsigned short* xh    = (unsigned short*)(ws + OFF_XH);
  unsigned short* h_buf = (unsigned short*)(ws + OFF_HBUF);
  float* c_state        = (float*)(ws + OFF_CST);
  unsigned short* u_part= (unsigned short*)(ws + OFF_UP);
  float* Z_part         = (float*)(ws + OFF_ZP);
  int* bars             = (int*)(ws + OFF_BARS);

  // zero the state that must start at 0 (ws is poisoned 0xAA each call)
  hipMemsetAsync(WkrT, 0, SZ_WKRT, stream);    // covers k-pad [1168,1184)
  hipMemsetAsync(xh, 0, SZ_XH, stream);        // h region + pad = 0
  hipMemsetAsync(h_buf, 0, SZ_HBUF, stream);
  hipMemsetAsync(c_state, 0, SZ_CST, stream);
  hipMemsetAsync(bars, 0, 1024 * sizeof(int), stream);

  // transposed bf16 weight copies
  k_transpose<<<dim3(8, 500), 256, 0, stream>>>(Ws, WsT, 512, 32000, 512, 0);
  k_transpose<<<dim3(500, 8), 256, 0, stream>>>(E, EbT, 32000, 512, 32000, 0);
  k_transpose<<<dim3(11, 32), 256, 0, stream>>>(Wk, WkrT, 656, 2048, 1184, 0);
  k_transpose<<<dim3(8, 32), 256, 0, stream>>>(Wr, WkrT, 512, 2048, 1184, 656);
  k_init<<<64, 256, 0, stream>>>(content, style, E, xh, out);

  void* args[] = { (void*)&bvec, (void*)&bs, (void*)&WsT, (void*)&EbT, (void*)&WkrT,
                   (void*)&xh, (void*)&h_buf, (void*)&c_state,
                   (void*)&u_part, (void*)&Z_part, (void*)&bars, (void*)&out };
  hipLaunchCooperativeKernel((void*)k_main, dim3(NWG), dim3(WG_SIZE), args, 0, stream);

  (void)in_sizes; (void)n_in; (void)out_size; (void)ws_size;
}

// Round 2
// 3462.838 us; speedup vs baseline: 1.7893x; 1.7893x over previous
//
#include <hip/hip_runtime.h>

#define T_STEPS 63
#define NWG 256
#define WG_SIZE 256

typedef float floatx4 __attribute__((ext_vector_type(4)));
typedef __bf16 bf16x8 __attribute__((ext_vector_type(8)));

__device__ __forceinline__ unsigned short f2bf(float x) {
  unsigned int u = __builtin_bit_cast(unsigned int, x);
  u += 0x7fffu + ((u >> 16) & 1u);
  return (unsigned short)(u >> 16);
}
__device__ __forceinline__ float bf2f(unsigned short h) {
  unsigned int u = ((unsigned int)h) << 16;
  return __builtin_bit_cast(float, u);
}
__device__ __forceinline__ float sigmoidf(float x) {
  return 1.0f / (1.0f + __expf(-x));
}
__device__ __forceinline__ floatx4 mfma_bf16(bf16x8 a, bf16x8 b, floatx4 c) {
  return __builtin_amdgcn_mfma_f32_16x16x32_bf16(a, b, c, 0, 0, 0);
}
__device__ __forceinline__ floatx4 mfma_fp8(long a, long b, floatx4 c) {
  return __builtin_amdgcn_mfma_f32_16x16x32_fp8_fp8(a, b, c, 0, 0, 0);
}
__device__ __forceinline__ unsigned char f2fp8(float x) {
  return (unsigned char)(__builtin_amdgcn_cvt_pk_fp8_f32(x, x, 0, false) & 0xff);
}

// ---- grid barrier (cooperative launch guarantees co-residency) ----
__device__ __forceinline__ void gbar(int* bars, int id, int n) {
  __syncthreads();
  if (threadIdx.x == 0) {
    __builtin_amdgcn_fence(__ATOMIC_RELEASE, "agent");
    __hip_atomic_fetch_add(bars + id, 1, __ATOMIC_RELAXED, __HIP_MEMORY_SCOPE_AGENT);
    while (__hip_atomic_load(bars + id, __ATOMIC_RELAXED, __HIP_MEMORY_SCOPE_AGENT) < n)
      __builtin_amdgcn_s_sleep(1);
    __builtin_amdgcn_fence(__ATOMIC_ACQUIRE, "agent");
  }
  __syncthreads();
}

// ---- prologue: tiled transpose fp32 -> bf16.  out[c*ostride + ooff + r] = bf16(in[r*C+c])
__global__ void k_transpose(const float* __restrict__ in, unsigned short* __restrict__ out,
                            int R, int C, int ostride, int ooff) {
  __shared__ unsigned short tile[64][65];
  const int r0 = blockIdx.x << 6, c0 = blockIdx.y << 6;
  const int t = threadIdx.x;
  const int tr4 = t >> 6, tc = t & 63;
#pragma unroll
  for (int p = 0; p < 16; ++p) {
    int i = (p << 2) + tr4;
    int r = r0 + i;
    unsigned short v = 0;
    if (r < R) v = f2bf(in[(size_t)r * C + (c0 + tc)]);
    tile[i][tc] = v;
  }
  __syncthreads();
#pragma unroll
  for (int p = 0; p < 16; ++p) {
    int j = (p << 2) + tr4;
    int r = r0 + tc;
    if (r < R) out[(size_t)(c0 + j) * ostride + ooff + r] = tile[tc][j];
  }
}

// ---- prologue: tiled transpose fp32 -> fp8.  out[c*OS + r] = fp8(in[r*C+c])
__global__ void k_transpose_fp8(const float* __restrict__ in, unsigned char* __restrict__ out,
                                int R, int C, long OS) {
  __shared__ unsigned char tile[64][68];
  const int r0 = blockIdx.x << 6, c0 = blockIdx.y << 6;
  const int t = threadIdx.x;
  const int tr4 = t >> 6, tc = t & 63;
#pragma unroll
  for (int p = 0; p < 16; ++p) {
    int i = (p << 2) + tr4;
    int r = r0 + i;
    float v = (r < R) ? in[(size_t)r * C + (c0 + tc)] : 0.f;
    tile[i][tc] = f2fp8(v);
  }
  __syncthreads();
#pragma unroll
  for (int p = 0; p < 16; ++p) {
    int j = (p << 2) + tr4;
    out[(size_t)(c0 + j) * OS + r0 + tc] = tile[tc][j];
  }
}

// ---- prologue: init xh (emb0 = E[0], content, style) and out[:,0,:] = E[0]
__global__ void k_init(const float* __restrict__ content, const float* __restrict__ style,
                       const float* __restrict__ E, unsigned short* xh, float* out) {
  const int stride = gridDim.x * blockDim.x;
  const int idx = blockIdx.x * blockDim.x + threadIdx.x;
  for (int i = idx; i < 32 * 656; i += stride) {
    int b = i / 656, k = i - b * 656;
    float v;
    if (k < 512)      v = E[k];
    else if (k < 640) v = content[b * 128 + (k - 512)];
    else              v = style[b * 16 + (k - 640)];
    xh[b * 1184 + k] = f2bf(v);
  }
  for (int i = idx; i < 32 * 512; i += stride) {
    int b = i >> 9, d = i & 511;
    out[(size_t)b * (64 * 512) + d] = E[d];
  }
}

// LDS layout (byte offsets), per-WG role:
//  vocab WG (wg>=32): Ws8  @0        [144][512] fp8, 8B-group XOR-swizzled by (row&7)
//                     E8T  @73728    [512][160] fp8, 8B-group rotated by (d%20)
//                     e_lds@155648   [32][160]  fp8
//  phaseA WG (wg<32): wkr  @0        [64][1192] bf16 (rows: gate*16 + local col)
//                     zbuf @152576   [4][32][16] f32
//  all:               phc  @160768   zred f32[256] + red f32[64*4]
#define SMEM_BYTES 162816
#define OFF_E8T_L 73728
#define OFF_ELDS_L 155648
#define OFF_ZBUF_L 152576
#define OFF_PHC_L 160768

__global__ void __launch_bounds__(WG_SIZE, 1) k_main(
    const float* __restrict__ bvec,          // [2048]
    const float* __restrict__ bs,            // [32000]
    const unsigned char* __restrict__ Ws8_g, // [32256][512] fp8 (Ws^T)
    const unsigned char* __restrict__ E8T_g, // [512][32768]  fp8 (E^T)
    const unsigned short* __restrict__ WkrT, // [2048][1184]  bf16 ([Wk;Wr]^T, k-padded)
    unsigned short* xh,      // [32][1184] bf16: emb | content | style | h | pad(0)
    unsigned short* h_bufg,  // [32][512] bf16
    unsigned char* h8,       // [32][512] fp8
    unsigned short* u_part,  // [224][32][512] bf16
    float* Z_part,           // [224][32] fp32
    int* bars, float* out)
{
  const int wg = blockIdx.x;
  const int t  = threadIdx.x;
  const int wv = t >> 6;
  const int lane = t & 63;
  const int q = lane >> 4;
  const int m16 = lane & 15;

  __shared__ __align__(16) char smem[SMEM_BYTES];
  unsigned char* lds_ws  = (unsigned char*)smem;
  unsigned char* lds_e8t = (unsigned char*)(smem + OFF_E8T_L);
  unsigned char* lds_e   = (unsigned char*)(smem + OFF_ELDS_L);
  unsigned short* lds_wkr = (unsigned short*)smem;
  float* zbuf = (float*)(smem + OFF_ZBUF_L);
  float* phc  = (float*)(smem + OFF_PHC_L);

  const int wgv = wg - 32;
  const long j0 = (long)(wgv < 0 ? 0 : wgv) * 144;

  // ---- one-time LDS fill ----
  float bias0 = 0.f, bias1 = 0.f, bias2 = 0.f, bias3 = 0.f;
  float c2[2] = {0.f, 0.f};
  if (wg < 32) {
    // wkr rows: row = g*16 + c  -> global n = g*512 + wg*16 + c ; 148 8-elem groups/row
    for (int idx = t; idx < 64 * 148; idx += WG_SIZE) {
      int row = idx / 148, grp = idx - row * 148;
      int g = row >> 4, c = row & 15;
      int n = g * 512 + (wg << 4) + c;
      ulong2 v = *(const ulong2*)(WkrT + (size_t)n * 1184 + grp * 8);
      *(ulong2*)(lds_wkr + row * 1192 + grp * 8) = v;
    }
    const int dl = t & 15;
    bias0 = bvec[0 * 512 + (wg << 4) + dl];
    bias1 = bvec[1 * 512 + (wg << 4) + dl];
    bias2 = bvec[2 * 512 + (wg << 4) + dl];
    bias3 = bvec[3 * 512 + (wg << 4) + dl];
  } else {
    // Ws8: 144 rows x 64 groups of 8 B, XOR swizzle
    for (int idx = t; idx < 144 * 64; idx += WG_SIZE) {
      int row = idx >> 6, grp = idx & 63;
      long v = *(const long*)(Ws8_g + (j0 + row) * 512 + grp * 8);
      *(long*)(lds_ws + row * 512 + ((grp ^ (row & 7)) << 3)) = v;
    }
    // E8T: 512 rows x 20 groups of 8 B (18 data + 2 zero K-pad), rotate by d%20
    for (int idx = t; idx < 512 * 20; idx += WG_SIZE) {
      int d = idx / 20, g = idx - d * 20;
      long v = 0;
      if (g < 18) v = *(const long*)(E8T_g + (size_t)d * 32768 + j0 + g * 8);
      int grp = g + (d % 20); if (grp >= 20) grp -= 20;
      *(long*)(lds_e8t + d * 160 + grp * 8) = v;
    }
    // zero e_lds (K-pad cols 144..160 must stay zero)
    for (int idx = t; idx < (32 * 160) / 8; idx += WG_SIZE) ((long*)lds_e)[idx] = 0;
  }

  int bar_id = 0;
  for (int s = 0; s < T_STEPS; ++s) {
    // ================ phase A: z = x @ Wkr + b ; LSTM pointwise ================
    if (wg < 32) {
      const int g = wv;  // wave = gate
      const unsigned short* wrow = lds_wkr + (g * 16 + m16) * 1192;
      const unsigned short* a0p = xh + m16 * 1184 + q * 8;
      const unsigned short* a1p = xh + (16 + m16) * 1184 + q * 8;
      floatx4 acc[2] = {{0,0,0,0},{0,0,0,0}};
#pragma unroll 4
      for (int ks = 0; ks < 37; ++ks) {
        bf16x8 bb = *(const bf16x8*)(wrow + ks * 32 + q * 8);
        bf16x8 a0 = *(const bf16x8*)(a0p + ks * 32);
        bf16x8 a1 = *(const bf16x8*)(a1p + ks * 32);
        acc[0] = mfma_bf16(a0, bb, acc[0]);
        acc[1] = mfma_bf16(a1, bb, acc[1]);
      }
#pragma unroll
      for (int mt = 0; mt < 2; ++mt)
#pragma unroll
        for (int r = 0; r < 4; ++r)
          zbuf[(g * 32 + mt * 16 + q * 4 + r) * 16 + m16] = acc[mt][r];
      __syncthreads();
      {
        const int dl = t & 15;
#pragma unroll
        for (int p = 0; p < 2; ++p) {
          const int b = (p * 256 + t) >> 4;
          float zi = zbuf[(0 * 32 + b) * 16 + dl] + bias0;
          float zf = zbuf[(1 * 32 + b) * 16 + dl] + bias1;
          float zg = zbuf[(2 * 32 + b) * 16 + dl] + bias2;
          float zo = zbuf[(3 * 32 + b) * 16 + dl] + bias3;
          float iv = sigmoidf(zi), fv = sigmoidf(zf);
          float gv = tanhf(zg),    ov = sigmoidf(zo);
          c2[p] = fv * c2[p] + iv * gv;
          float h = ov * tanhf(c2[p]);
          int d = (wg << 4) + dl;
          h_bufg[b * 512 + d] = f2bf(h);
          h8[b * 512 + d] = f2fp8(h);
        }
      }
    }
    gbar(bars, bar_id++, NWG);

    // ================ phase B: vocab slice (logits -> exp -> u partial) ========
    if (wg >= 32) {
      // preload A frags (h8, all 512 k) into registers
      long ah[2][16];
#pragma unroll
      for (int mt = 0; mt < 2; ++mt)
#pragma unroll
        for (int ks = 0; ks < 16; ++ks)
          ah[mt][ks] = *(const long*)(h8 + (mt * 16 + m16) * 512 + ks * 32 + q * 8);
      // logits: 9 n-tiles round-robin over waves
      for (int tile = wv; tile < 9; tile += 4) {
        const int jl = tile * 16 + m16;
        const unsigned char* wrow = lds_ws + jl * 512;
        const int sw = jl & 7;
        floatx4 acc[2] = {{0,0,0,0},{0,0,0,0}};
#pragma unroll
        for (int ks = 0; ks < 16; ++ks) {
          int g = ks * 4 + q;
          long bfrag = *(const long*)(wrow + ((g ^ sw) << 3));
          acc[0] = mfma_fp8(ah[0][ks], bfrag, acc[0]);
          acc[1] = mfma_fp8(ah[1][ks], bfrag, acc[1]);
        }
        const long jg = j0 + jl;
        const float bsv = bs[jg < 32000 ? jg : 31999];
        const bool valid = (jg < 32000);
#pragma unroll
        for (int mt = 0; mt < 2; ++mt)
#pragma unroll
          for (int r = 0; r < 4; ++r) {
            float e = valid ? __expf(acc[mt][r] + bsv) : 0.0f;
            lds_e[(mt * 16 + q * 4 + r) * 160 + jl] = f2fp8(e);
          }
      }
      __syncthreads();
      // Z partials (wave 3, threads 192..223), from the SAME fp8-rounded e
      if (t >= 192 && t < 224) {
        const int b = t - 192;
        const unsigned int* rowp = (const unsigned int*)(lds_e + b * 160);
        float z = 0.f;
        for (int g = 0; g < 36; ++g) {
          int w4 = (int)rowp[g];
          z += __builtin_amdgcn_cvt_f32_fp8(w4, 0) + __builtin_amdgcn_cvt_f32_fp8(w4, 1)
             + __builtin_amdgcn_cvt_f32_fp8(w4, 2) + __builtin_amdgcn_cvt_f32_fp8(w4, 3);
        }
        Z_part[wgv * 32 + b] = z;
      }
      // PV: u partial = e @ E_slice
      long ae[2][5];
#pragma unroll
      for (int mt = 0; mt < 2; ++mt)
#pragma unroll
        for (int ks = 0; ks < 5; ++ks)
          ae[mt][ks] = *(const long*)(lds_e + (mt * 16 + m16) * 160 + ks * 32 + q * 8);
      for (int nt = wv; nt < 32; nt += 4) {
        const int d = nt * 16 + m16;
        const int dm = d % 20;
        const unsigned char* erow = lds_e8t + d * 160;
        floatx4 acc2[2] = {{0,0,0,0},{0,0,0,0}};
#pragma unroll
        for (int ks = 0; ks < 5; ++ks) {
          int g = ks * 4 + q + dm; if (g >= 20) g -= 20;
          long bfrag = *(const long*)(erow + (g << 3));
          acc2[0] = mfma_fp8(ae[0][ks], bfrag, acc2[0]);
          acc2[1] = mfma_fp8(ae[1][ks], bfrag, acc2[1]);
        }
#pragma unroll
        for (int mt = 0; mt < 2; ++mt)
#pragma unroll
          for (int r = 0; r < 4; ++r) {
            int b = mt * 16 + q * 4 + r;
            u_part[((size_t)(wgv * 32 + b)) * 512 + d] = f2bf(acc2[mt][r]);
          }
      }
    }
    gbar(bars, bar_id++, NWG);

    // ================ phase C: reduce partials -> emb ; stage next xh ==========
    {
      float* zred = phc;        // [256]
      float* red  = phc + 256;  // [64][4]
      const int b = wg >> 3;
      const int tl = t & 63;
      const int d = ((wg & 7) << 6) + tl;
      zred[t] = (t < 224) ? Z_part[t * 32 + b] : 0.f;
      __syncthreads();
      for (int st = 128; st > 0; st >>= 1) {
        if (t < st) zred[t] += zred[t + st];
        __syncthreads();
      }
      const float invZ = 1.0f / zred[0];
      float ssum = 0.f;
      const int p0 = wv * 56;
      for (int p = p0; p < p0 + 56; ++p)
        ssum += bf2f(u_part[((size_t)(p * 32 + b)) * 512 + d]);
      red[tl * 4 + wv] = ssum;
      __syncthreads();
      if (t < 64) {
        const int dd = ((wg & 7) << 6) + t;
        const float emb = (red[t * 4 + 0] + red[t * 4 + 1] + red[t * 4 + 2] + red[t * 4 + 3]) * invZ;
        out[(size_t)b * (64 * 512) + (size_t)(s + 1) * 512 + dd] = emb;
        xh[b * 1184 + dd] = f2bf(emb);
        xh[b * 1184 + 656 + dd] = h_bufg[b * 512 + dd];
      }
    }
    if (s < T_STEPS - 1) gbar(bars, bar_id++, NWG);
  }
}

// ---------------- host ----------------
extern "C" void kernel_launch(void* const* d_in, const int* in_sizes, int n_in,
                              void* d_out, int out_size, void* d_ws, size_t ws_size,
                              hipStream_t stream) {
  const float* content = (const float*)d_in[0];
  const float* style   = (const float*)d_in[1];
  const float* E       = (const float*)d_in[2];
  const float* Wk      = (const float*)d_in[3];
  const float* Wr      = (const float*)d_in[4];
  const float* bvec    = (const float*)d_in[5];
  const float* Ws      = (const float*)d_in[6];
  const float* bs      = (const float*)d_in[7];
  float* out = (float*)d_out;
  char* ws = (char*)d_ws;

  constexpr size_t SZ_WS8  = 32256ull * 512;           // 16,515,072
  constexpr size_t SZ_E8T  = 512ull * 32768;           // 16,777,216
  constexpr size_t SZ_WKRT = 2048ull * 1184 * 2;       //  4,849,664
  constexpr size_t SZ_XH   = 32ull * 1184 * 2;         //     75,776
  constexpr size_t SZ_HBUF = 32ull * 512 * 2;          //     32,768
  constexpr size_t SZ_H8   = 32ull * 512;              //     16,384
  constexpr size_t SZ_UP   = 224ull * 32 * 512 * 2;    //  7,340,032
  constexpr size_t SZ_ZP   = 224ull * 32 * 4;          //     28,672
  constexpr size_t OFF_WS8  = 0;
  constexpr size_t OFF_E8T  = OFF_WS8 + SZ_WS8;
  constexpr size_t OFF_WKRT = OFF_E8T + SZ_E8T;
  constexpr size_t OFF_XH   = OFF_WKRT + SZ_WKRT;
  constexpr size_t OFF_HBUF = OFF_XH + SZ_XH;
  constexpr size_t OFF_H8   = OFF_HBUF + SZ_HBUF;
  constexpr size_t OFF_UP   = OFF_H8 + SZ_H8;
  constexpr size_t OFF_ZP   = OFF_UP + SZ_UP;
  constexpr size_t OFF_BARS = OFF_ZP + SZ_ZP + 256;

  unsigned char*  Ws8_g = (unsigned char*)(ws + OFF_WS8);
  unsigned char*  E8T_g = (unsigned char*)(ws + OFF_E8T);
  unsigned short* WkrT  = (unsigned short*)(ws + OFF_WKRT);
  unsigned short* xh    = (unsigned short*)(ws + OFF_XH);
  unsigned short* h_buf = (unsigned short*)(ws + OFF_HBUF);
  unsigned char*  h8    = (unsigned char*)(ws + OFF_H8);
  unsigned short* u_part= (unsigned short*)(ws + OFF_UP);
  float* Z_part         = (float*)(ws + OFF_ZP);
  int* bars             = (int*)(ws + OFF_BARS);

  // zero state (ws is poisoned 0xAA each call)
  hipMemsetAsync(Ws8_g, 0, SZ_WS8, stream);   // covers j-pad rows 32000..32256
  hipMemsetAsync(E8T_g, 0, SZ_E8T, stream);   // covers j-pad cols 32000..32768
  hipMemsetAsync(WkrT, 0, SZ_WKRT, stream);   // covers k-pad [1168,1184)
  hipMemsetAsync(xh, 0, SZ_XH, stream);       // h region + pad = 0
  hipMemsetAsync(bars, 0, 1024 * sizeof(int), stream);

  // transposed weight copies
  k_transpose_fp8<<<dim3(8, 500), 256, 0, stream>>>(Ws, Ws8_g, 512, 32000, 512);
  k_transpose_fp8<<<dim3(500, 8), 256, 0, stream>>>(E, E8T_g, 32000, 512, 32768);
  k_transpose<<<dim3(11, 32), 256, 0, stream>>>(Wk, WkrT, 656, 2048, 1184, 0);
  k_transpose<<<dim3(8, 32), 256, 0, stream>>>(Wr, WkrT, 512, 2048, 1184, 656);
  k_init<<<64, 256, 0, stream>>>(content, style, E, xh, out);

  void* args[] = { (void*)&bvec, (void*)&bs, (void*)&Ws8_g, (void*)&E8T_g, (void*)&WkrT,
                   (void*)&xh, (void*)&h_buf, (void*)&h8,
                   (void*)&u_part, (void*)&Z_part, (void*)&bars, (void*)&out };
  hipLaunchCooperativeKernel((void*)k_main, dim3(NWG), dim3(WG_SIZE), args, 0, stream);

  (void)in_sizes; (void)n_in; (void)out_size; (void)ws_size;
}

// Round 3
// 3259.492 us; speedup vs baseline: 1.9009x; 1.0624x over previous
//
#include <hip/hip_runtime.h>

#define T_STEPS 63
#define NWG 256
#define WG_SIZE 256
#define NA 32
#define NV 224

typedef float floatx4 __attribute__((ext_vector_type(4)));
typedef __bf16 bf16x8 __attribute__((ext_vector_type(8)));

__device__ __forceinline__ unsigned short f2bf(float x) {
  unsigned int u = __builtin_bit_cast(unsigned int, x);
  u += 0x7fffu + ((u >> 16) & 1u);
  return (unsigned short)(u >> 16);
}
__device__ __forceinline__ float sigmoidf(float x) {
  return 1.0f / (1.0f + __expf(-x));
}
__device__ __forceinline__ floatx4 mfma_bf16(bf16x8 a, bf16x8 b, floatx4 c) {
  return __builtin_amdgcn_mfma_f32_16x16x32_bf16(a, b, c, 0, 0, 0);
}
__device__ __forceinline__ floatx4 mfma_fp8(long a, long b, floatx4 c) {
  return __builtin_amdgcn_mfma_f32_16x16x32_fp8_fp8(a, b, c, 0, 0, 0);
}
__device__ __forceinline__ unsigned char f2fp8(float x) {
  return (unsigned char)(__builtin_amdgcn_cvt_pk_fp8_f32(x, x, 0, false) & 0xff);
}

// ---- device-scope (MALL, sc0|sc1) relaxed atomics: no fences, no L2 staleness ----
__device__ __forceinline__ unsigned long long ald64(const void* p) {
  return __hip_atomic_load((const unsigned long long*)p, __ATOMIC_RELAXED, __HIP_MEMORY_SCOPE_AGENT);
}
__device__ __forceinline__ float aldf(const float* p) {
  return __hip_atomic_load(p, __ATOMIC_RELAXED, __HIP_MEMORY_SCOPE_AGENT);
}
__device__ __forceinline__ void astf(float* p, float v) {
  __hip_atomic_store(p, v, __ATOMIC_RELAXED, __HIP_MEMORY_SCOPE_AGENT);
}
__device__ __forceinline__ void astu16(unsigned short* p, unsigned short v) {
  __hip_atomic_store(p, v, __ATOMIC_RELAXED, __HIP_MEMORY_SCOPE_AGENT);
}
__device__ __forceinline__ void astu8(unsigned char* p, unsigned char v) {
  __hip_atomic_store(p, v, __ATOMIC_RELAXED, __HIP_MEMORY_SCOPE_AGENT);
}
__device__ __forceinline__ void afaddf(float* p, float v) {
  __hip_atomic_fetch_add(p, v, __ATOMIC_RELAXED, __HIP_MEMORY_SCOPE_AGENT);
}
__device__ __forceinline__ bf16x8 ld_bf8_at(const void* p) {
  union { unsigned long long q[2]; bf16x8 v; } u;
  u.q[0] = ald64(p);
  u.q[1] = ald64((const char*)p + 8);
  return u.v;
}

// signal: drain this WG's vmem (write-through stores/atomics already at MALL), then +1
__device__ __forceinline__ void signal_flag(int* f) {
  __builtin_amdgcn_s_waitcnt(0);
  __syncthreads();
  if (threadIdx.x == 0)
    __hip_atomic_fetch_add(f, 1, __ATOMIC_RELAXED, __HIP_MEMORY_SCOPE_AGENT);
}
__device__ __forceinline__ void wait_flag(const int* f, int target) {
  if (threadIdx.x == 0) {
    while (__hip_atomic_load(f, __ATOMIC_RELAXED, __HIP_MEMORY_SCOPE_AGENT) < target)
      __builtin_amdgcn_s_sleep(2);
  }
  __syncthreads();
}

// ---- prologue: tiled transpose fp32 -> bf16.  out[c*ostride + ooff + r] = bf16(in[r*C+c])
__global__ void k_transpose(const float* __restrict__ in, unsigned short* __restrict__ out,
                            int R, int C, int ostride, int ooff) {
  __shared__ unsigned short tile[64][65];
  const int r0 = blockIdx.x << 6, c0 = blockIdx.y << 6;
  const int t = threadIdx.x;
  const int tr4 = t >> 6, tc = t & 63;
#pragma unroll
  for (int p = 0; p < 16; ++p) {
    int i = (p << 2) + tr4;
    int r = r0 + i;
    unsigned short v = 0;
    if (r < R) v = f2bf(in[(size_t)r * C + (c0 + tc)]);
    tile[i][tc] = v;
  }
  __syncthreads();
#pragma unroll
  for (int p = 0; p < 16; ++p) {
    int j = (p << 2) + tr4;
    int r = r0 + tc;
    if (r < R) out[(size_t)(c0 + j) * ostride + ooff + r] = tile[tc][j];
  }
}

// ---- prologue: tiled transpose fp32 -> fp8.  out[c*OS + r] = fp8(in[r*C+c])
__global__ void k_transpose_fp8(const float* __restrict__ in, unsigned char* __restrict__ out,
                                int R, int C, long OS) {
  __shared__ unsigned char tile[64][68];
  const int r0 = blockIdx.x << 6, c0 = blockIdx.y << 6;
  const int t = threadIdx.x;
  const int tr4 = t >> 6, tc = t & 63;
#pragma unroll
  for (int p = 0; p < 16; ++p) {
    int i = (p << 2) + tr4;
    int r = r0 + i;
    float v = (r < R) ? in[(size_t)r * C + (c0 + tc)] : 0.f;
    tile[i][tc] = f2fp8(v);
  }
  __syncthreads();
#pragma unroll
  for (int p = 0; p < 16; ++p) {
    int j = (p << 2) + tr4;
    out[(size_t)(c0 + j) * OS + r0 + tc] = tile[tc][j];
  }
}

// ---- prologue: cs_bf[32][160] = bf16(content|style|pad0); out[:,0,:] = E[0]
__global__ void k_init(const float* __restrict__ content, const float* __restrict__ style,
                       const float* __restrict__ E, unsigned short* cs_bf, float* out) {
  const int stride = gridDim.x * blockDim.x;
  const int idx = blockIdx.x * blockDim.x + threadIdx.x;
  for (int i = idx; i < 32 * 160; i += stride) {
    int b = i / 160, k = i - b * 160;
    float v = 0.f;
    if (k < 128)      v = content[b * 128 + k];
    else if (k < 144) v = style[b * 16 + (k - 128)];
    cs_bf[i] = f2bf(v);
  }
  for (int i = idx; i < 32 * 512; i += stride) {
    int b = i >> 9, d = i & 511;
    out[(size_t)b * (64 * 512) + d] = E[d];
  }
}

// LDS layout (byte offsets), per-WG role:
//  vocab WG (wg>=32): Ws8  @0        [144][512] fp8, 8B-group XOR-swizzled by (row&7)
//                     E8T  @73728    [512][160] fp8, 8B-group rotated by (d%20)
//                     e_lds@155648   [32][160]  fp8
//  A WG (wg<32):      wkr  @0        [64][1192] bf16 (rows: gate*16 + d-local)
//                     zbuf @152576   [4][32][16] f32
#define SMEM_BYTES 160768
#define OFF_E8T_L 73728
#define OFF_ELDS_L 155648
#define OFF_ZBUF_L 152576

__global__ void __launch_bounds__(WG_SIZE, 1) k_main(
    const float* __restrict__ bvec,          // [2048]
    const float* __restrict__ bs,            // [32000]
    const unsigned char* __restrict__ Ws8_g, // [32256][512] fp8 (Ws^T)
    const unsigned char* __restrict__ E8T_g, // [512][32768]  fp8 (E^T)
    const unsigned short* __restrict__ WkrT, // [2048][1184]  bf16, k = emb512|cs144|pad16|h512
    const unsigned short* __restrict__ cs_bf,// [32][160] bf16 (content|style|pad0)
    const float* __restrict__ E,             // [32000][512] fp32 (row 0 used at s=0)
    unsigned short* h_bufg,  // [32][512] bf16
    unsigned char* h8,       // [32][512] fp8
    float* u,                // [2][32][512] fp32 accumulators (atomic)
    float* Zbuf,             // [2][32] fp32 accumulators (atomic)
    int* hflag, int* pflag,  // [64] stride-16 ints each
    float* out)
{
  const int wg = blockIdx.x;
  const int t  = threadIdx.x;
  const int wv = t >> 6;
  const int lane = t & 63;
  const int q = lane >> 4;
  const int m16 = lane & 15;

  __shared__ __align__(16) char smem[SMEM_BYTES];
  unsigned char* lds_ws  = (unsigned char*)smem;
  unsigned char* lds_e8t = (unsigned char*)(smem + OFF_E8T_L);
  unsigned char* lds_e   = (unsigned char*)(smem + OFF_ELDS_L);
  unsigned short* lds_wkr = (unsigned short*)smem;
  float* zbuf = (float*)(smem + OFF_ZBUF_L);

  if (wg < NA) {
    // ---------------- A-WG: LSTM owner of d-slice [wg*16, wg*16+16) ----------------
    for (int idx = t; idx < 64 * 148; idx += WG_SIZE) {
      int row = idx / 148, grp = idx - row * 148;
      int g = row >> 4, c = row & 15;
      int n = g * 512 + (wg << 4) + c;
      ulong2 v = *(const ulong2*)(WkrT + (size_t)n * 1184 + grp * 8);
      *(ulong2*)((char*)lds_wkr + row * 2384 + grp * 16) = v;
    }
    const int dl = t & 15;
    const float bias0 = bvec[0 * 512 + (wg << 4) + dl];
    const float bias1 = bvec[1 * 512 + (wg << 4) + dl];
    const float bias2 = bvec[2 * 512 + (wg << 4) + dl];
    const float bias3 = bvec[3 * 512 + (wg << 4) + dl];
    float c2[2] = {0.f, 0.f};
    __syncthreads();

    const int mt = wv & 1, g0 = (wv >> 1) << 1;
    const int row = mt * 16 + m16;
    const unsigned short* b0row = lds_wkr + (g0 * 16 + m16) * 1192;
    const unsigned short* b1row = lds_wkr + ((g0 + 1) * 16 + m16) * 1192;
    const int d = (wg << 4) + dl;

    for (int s = 0; s < T_STEPS; ++s) {
      const int pr = (s - 1) & 1;   // parity of emb(s) source / buffers to re-zero
      const int pc = s & 1;         // parity vocab fills this step
      floatx4 accG0 = {0.f, 0.f, 0.f, 0.f}, accG1 = {0.f, 0.f, 0.f, 0.f};
      // --- emb chunks (k 0..511) ---
      if (s == 0) {
#pragma unroll 4
        for (int ks = 0; ks < 16; ++ks) {
          const float* ep = E + ks * 32 + q * 8;
          bf16x8 a;
#pragma unroll
          for (int i = 0; i < 8; ++i) a[i] = (__bf16)ep[i];
          accG0 = mfma_bf16(a, *(const bf16x8*)(b0row + ks * 32 + q * 8), accG0);
          accG1 = mfma_bf16(a, *(const bf16x8*)(b1row + ks * 32 + q * 8), accG1);
        }
      } else {
        const float invZ = 1.0f / aldf(Zbuf + pr * 32 + row);
        const float* urow = u + pr * 16384 + row * 512 + q * 8;
#pragma unroll 4
        for (int ks = 0; ks < 16; ++ks) {
          union { unsigned long long w[4]; float f[8]; } uf;
#pragma unroll
          for (int i = 0; i < 4; ++i) uf.w[i] = ald64(urow + ks * 32 + i * 2);
          bf16x8 a;
#pragma unroll
          for (int i = 0; i < 8; ++i) a[i] = (__bf16)(uf.f[i] * invZ);
          accG0 = mfma_bf16(a, *(const bf16x8*)(b0row + ks * 32 + q * 8), accG0);
          accG1 = mfma_bf16(a, *(const bf16x8*)(b1row + ks * 32 + q * 8), accG1);
        }
      }
      // --- content/style chunks (k 512..671, pad zeros) ---
#pragma unroll
      for (int ks = 16; ks < 21; ++ks) {
        bf16x8 a = *(const bf16x8*)(cs_bf + row * 160 + (ks - 16) * 32 + q * 8);
        accG0 = mfma_bf16(a, *(const bf16x8*)(b0row + ks * 32 + q * 8), accG0);
        accG1 = mfma_bf16(a, *(const bf16x8*)(b1row + ks * 32 + q * 8), accG1);
      }
      // --- h chunks (k 672..1183) ---
      if (s > 0) {
#pragma unroll 4
        for (int ks = 21; ks < 37; ++ks) {
          bf16x8 a = ld_bf8_at(h_bufg + row * 512 + (ks - 21) * 32 + q * 8);
          accG0 = mfma_bf16(a, *(const bf16x8*)(b0row + ks * 32 + q * 8), accG0);
          accG1 = mfma_bf16(a, *(const bf16x8*)(b1row + ks * 32 + q * 8), accG1);
        }
      }
      // --- exchange z via LDS (wave owns (gate-pair, m-tile)) ---
#pragma unroll
      for (int r = 0; r < 4; ++r) {
        zbuf[(g0 * 32 + mt * 16 + q * 4 + r) * 16 + m16] = accG0[r];
        zbuf[((g0 + 1) * 32 + mt * 16 + q * 4 + r) * 16 + m16] = accG1[r];
      }
      __syncthreads();
      // --- LSTM pointwise; stage h (write-through) ---
#pragma unroll
      for (int pp = 0; pp < 2; ++pp) {
        const int b = (pp * 256 + t) >> 4;
        float zi = zbuf[(0 * 32 + b) * 16 + dl] + bias0;
        float zf = zbuf[(1 * 32 + b) * 16 + dl] + bias1;
        float zg = zbuf[(2 * 32 + b) * 16 + dl] + bias2;
        float zo = zbuf[(3 * 32 + b) * 16 + dl] + bias3;
        float iv = sigmoidf(zi), fv = sigmoidf(zf);
        float gv = tanhf(zg),    ov = sigmoidf(zo);
        c2[pp] = fv * c2[pp] + iv * gv;
        float h = ov * tanhf(c2[pp]);
        astu16(h_bufg + b * 512 + d, f2bf(h));
        astu8(h8 + b * 512 + d, f2fp8(h));
      }
      signal_flag(hflag + s * 16);
      wait_flag(pflag + s * 16, NV);
      // --- re-zero consumed buffers (safe: all A-WGs' reads of parity pr are done,
      //     vocab reuses parity pr only after hflag(s+1)==32) ---
#pragma unroll
      for (int pp = 0; pp < 2; ++pp) {
        const int b = (pp * 256 + t) >> 4;
        astf(u + pr * 16384 + b * 512 + d, 0.0f);
      }
      if (t == 0) astf(Zbuf + pr * 32 + wg, 0.0f);
      // --- emb(s+1) -> out ---
#pragma unroll
      for (int pp = 0; pp < 2; ++pp) {
        const int b = (pp * 256 + t) >> 4;
        float uv = aldf(u + pc * 16384 + b * 512 + d);
        float Zv = aldf(Zbuf + pc * 32 + b);
        out[(size_t)b * (64 * 512) + (size_t)(s + 1) * 512 + d] = uv / Zv;
      }
    }
  } else {
    // ---------------- vocab WG: 144-word slice ----------------
    const int wgv = wg - NA;
    const long j0 = (long)wgv * 144;
    for (int idx = t; idx < 144 * 64; idx += WG_SIZE) {
      int row = idx >> 6, grp = idx & 63;
      long v = *(const long*)(Ws8_g + (j0 + row) * 512 + grp * 8);
      *(long*)(lds_ws + row * 512 + ((grp ^ (row & 7)) << 3)) = v;
    }
    for (int idx = t; idx < 512 * 20; idx += WG_SIZE) {
      int dd = idx / 20, g = idx - dd * 20;
      long v = 0;
      if (g < 18) v = *(const long*)(E8T_g + (size_t)dd * 32768 + j0 + g * 8);
      int grp = g + (dd % 20); if (grp >= 20) grp -= 20;
      *(long*)(lds_e8t + dd * 160 + grp * 8) = v;
    }
    for (int idx = t; idx < (32 * 160) / 8; idx += WG_SIZE) ((long*)lds_e)[idx] = 0;
    __syncthreads();

    for (int s = 0; s < T_STEPS; ++s) {
      wait_flag(hflag + s * 16, NA);
      const int pc = s & 1;
      long ah[2][16];
#pragma unroll
      for (int mt = 0; mt < 2; ++mt)
#pragma unroll
        for (int ks = 0; ks < 16; ++ks)
          ah[mt][ks] = (long)ald64(h8 + (mt * 16 + m16) * 512 + ks * 32 + q * 8);
      // logits: 9 n-tiles round-robin over waves
      for (int tile = wv; tile < 9; tile += 4) {
        const int jl = tile * 16 + m16;
        const unsigned char* wrow = lds_ws + jl * 512;
        const int sw = jl & 7;
        floatx4 acc[2] = {{0,0,0,0},{0,0,0,0}};
#pragma unroll
        for (int ks = 0; ks < 16; ++ks) {
          int g = ks * 4 + q;
          long bfrag = *(const long*)(wrow + ((g ^ sw) << 3));
          acc[0] = mfma_fp8(ah[0][ks], bfrag, acc[0]);
          acc[1] = mfma_fp8(ah[1][ks], bfrag, acc[1]);
        }
        const long jg = j0 + jl;
        const float bsv = bs[jg < 32000 ? jg : 31999];
        const bool valid = (jg < 32000);
#pragma unroll
        for (int mt = 0; mt < 2; ++mt)
#pragma unroll
          for (int r = 0; r < 4; ++r) {
            float e = valid ? __expf(acc[mt][r] + bsv) : 0.0f;
            lds_e[(mt * 16 + q * 4 + r) * 160 + jl] = f2fp8(e);
          }
      }
      __syncthreads();
      // Z partial from the SAME fp8-rounded e (wave 3, lanes 0..31)
      if (t >= 192 && t < 224) {
        const int b = t - 192;
        const unsigned int* rowp = (const unsigned int*)(lds_e + b * 160);
        float z = 0.f;
        for (int g = 0; g < 36; ++g) {
          int w4 = (int)rowp[g];
          z += __builtin_amdgcn_cvt_f32_fp8(w4, 0) + __builtin_amdgcn_cvt_f32_fp8(w4, 1)
             + __builtin_amdgcn_cvt_f32_fp8(w4, 2) + __builtin_amdgcn_cvt_f32_fp8(w4, 3);
        }
        afaddf(Zbuf + pc * 32 + b, z);
      }
      // PV: u += e @ E_slice (atomic fp32 accumulate at MALL)
      long ae[2][5];
#pragma unroll
      for (int mt = 0; mt < 2; ++mt)
#pragma unroll
        for (int ks = 0; ks < 5; ++ks)
          ae[mt][ks] = *(const long*)(lds_e + (mt * 16 + m16) * 160 + ks * 32 + q * 8);
      for (int nt = wv; nt < 32; nt += 4) {
        const int dd = nt * 16 + m16;
        const int dm = dd % 20;
        const unsigned char* erow = lds_e8t + dd * 160;
        floatx4 acc2[2] = {{0,0,0,0},{0,0,0,0}};
#pragma unroll
        for (int ks = 0; ks < 5; ++ks) {
          int g = ks * 4 + q + dm; if (g >= 20) g -= 20;
          long bfrag = *(const long*)(erow + (g << 3));
          acc2[0] = mfma_fp8(ae[0][ks], bfrag, acc2[0]);
          acc2[1] = mfma_fp8(ae[1][ks], bfrag, acc2[1]);
        }
#pragma unroll
        for (int mt = 0; mt < 2; ++mt)
#pragma unroll
          for (int r = 0; r < 4; ++r)
            afaddf(u + pc * 16384 + (mt * 16 + q * 4 + r) * 512 + dd, acc2[mt][r]);
      }
      signal_flag(pflag + s * 16);
    }
  }
}

// ---------------- host ----------------
extern "C" void kernel_launch(void* const* d_in, const int* in_sizes, int n_in,
                              void* d_out, int out_size, void* d_ws, size_t ws_size,
                              hipStream_t stream) {
  const float* content = (const float*)d_in[0];
  const float* style   = (const float*)d_in[1];
  const float* E       = (const float*)d_in[2];
  const float* Wk      = (const float*)d_in[3];
  const float* Wr      = (const float*)d_in[4];
  const float* bvec    = (const float*)d_in[5];
  const float* Ws      = (const float*)d_in[6];
  const float* bs      = (const float*)d_in[7];
  float* out = (float*)d_out;
  char* ws = (char*)d_ws;

  constexpr size_t SZ_WS8  = 32256ull * 512;           // 16,515,072
  constexpr size_t SZ_E8T  = 512ull * 32768;           // 16,777,216
  constexpr size_t SZ_WKRT = 2048ull * 1184 * 2;       //  4,849,664
  constexpr size_t SZ_CS   = 32ull * 160 * 2;          //     10,240
  constexpr size_t SZ_HB   = 32ull * 512 * 2;          //     32,768
  constexpr size_t SZ_H8   = 32ull * 512;              //     16,384
  constexpr size_t SZ_U    = 2ull * 32 * 512 * 4;      //    131,072
  constexpr size_t SZ_ZB   = 2ull * 32 * 4;            //        256
  constexpr size_t SZ_FLAG = 2ull * 64 * 16 * 4;       //      8,192
  constexpr size_t OFF_WS8  = 0;
  constexpr size_t OFF_E8T  = OFF_WS8 + SZ_WS8;
  constexpr size_t OFF_WKRT = OFF_E8T + SZ_E8T;
  constexpr size_t OFF_CS   = OFF_WKRT + SZ_WKRT;
  constexpr size_t OFF_HB   = OFF_CS + SZ_CS;
  constexpr size_t OFF_H8   = OFF_HB + SZ_HB;
  constexpr size_t OFF_U    = OFF_H8 + SZ_H8;
  constexpr size_t OFF_ZB   = OFF_U + SZ_U;
  constexpr size_t OFF_FLAG = OFF_ZB + SZ_ZB;

  unsigned char*  Ws8_g = (unsigned char*)(ws + OFF_WS8);
  unsigned char*  E8T_g = (unsigned char*)(ws + OFF_E8T);
  unsigned short* WkrT  = (unsigned short*)(ws + OFF_WKRT);
  unsigned short* cs_bf = (unsigned short*)(ws + OFF_CS);
  unsigned short* h_bufg= (unsigned short*)(ws + OFF_HB);
  unsigned char*  h8    = (unsigned char*)(ws + OFF_H8);
  float* u              = (float*)(ws + OFF_U);
  float* Zbuf           = (float*)(ws + OFF_ZB);
  int* hflag            = (int*)(ws + OFF_FLAG);
  int* pflag            = (int*)(ws + OFF_FLAG + SZ_FLAG / 2);

  // zero state (ws poisoned 0xAA each call)
  hipMemsetAsync(Ws8_g, 0, SZ_WS8, stream);   // covers j-pad rows 32000..32256
  hipMemsetAsync(E8T_g, 0, SZ_E8T, stream);   // covers j-pad cols 32000..32768
  hipMemsetAsync(WkrT, 0, SZ_WKRT, stream);   // covers k-pads 656..672, 1184 tail
  hipMemsetAsync(u, 0, SZ_U + SZ_ZB + SZ_FLAG + 256, stream); // u, Zbuf, flags

  // transposed weight copies; Wkr k-layout = Wk(656) | pad16 | Wr(512)
  k_transpose_fp8<<<dim3(8, 500), 256, 0, stream>>>(Ws, Ws8_g, 512, 32000, 512);
  k_transpose_fp8<<<dim3(500, 8), 256, 0, stream>>>(E, E8T_g, 32000, 512, 32768);
  k_transpose<<<dim3(11, 32), 256, 0, stream>>>(Wk, WkrT, 656, 2048, 1184, 0);
  k_transpose<<<dim3(8, 32), 256, 0, stream>>>(Wr, WkrT, 512, 2048, 1184, 672);
  k_init<<<64, 256, 0, stream>>>(content, style, E, cs_bf, out);

  void* args[] = { (void*)&bvec, (void*)&bs, (void*)&Ws8_g, (void*)&E8T_g, (void*)&WkrT,
                   (void*)&cs_bf, (void*)&E, (void*)&h_bufg, (void*)&h8,
                   (void*)&u, (void*)&Zbuf, (void*)&hflag, (void*)&pflag, (void*)&out };
  hipLaunchCooperativeKernel((void*)k_main, dim3(NWG), dim3(WG_SIZE), args, 0, stream);

  (void)in_sizes; (void)n_in; (void)out_size; (void)ws_size;
}